// Round 1
// baseline (1486.553 us; speedup 1.0000x reference)
//
#include <hip/hip_runtime.h>
#include <hip/hip_bf16.h>

// Problem constants
#define B_  4
#define S_  1024
#define D_  1024
#define H_  16
#define DH_ 64
#define N_  64          // B*H
#define BS_ 4096        // B*S

// Workspace layout (bytes)
#define WC_OFF   0ull                                // 3 x 1M floats = 12 MB
#define CUR_OFF  (WC_OFF + 3ull*1024*1024*4)         // 3 x [64][1024][64] f32 = 48 MB
#define MSK_OFF  (CUR_OFF + 3ull*64*1024*64*4)       // 3 x [64][1024] u64 = 1.5 MB
#define CTX_OFF  (MSK_OFF + 3ull*64*1024*8)          // [4096][1024] f32 = 16 MB

// ---------------------------------------------------------------------------
// Stage 0: combined projection weights Wc[m][h*64+d] = sum_j W[h*64+j][m] * Win[d][j]
// ---------------------------------------------------------------------------
__global__ __launch_bounds__(256) void k_wc(
    const float* __restrict__ Wq, const float* __restrict__ Wk, const float* __restrict__ Wv,
    const float* __restrict__ Wqi, const float* __restrict__ Wki, const float* __restrict__ Wvi,
    float* __restrict__ Wc)
{
    int z = blockIdx.y;
    const float* W  = (z == 0) ? Wq  : (z == 1) ? Wk  : Wv;
    const float* Wi = (z == 0) ? Wqi : (z == 1) ? Wki : Wvi;
    float* out = Wc + (size_t)z * 1024 * 1024;
    int o  = blockIdx.x * 256 + threadIdx.x;   // 0..1M-1
    int m  = o >> 10;
    int hd = o & 1023;
    int h  = hd >> 6, d = hd & 63;
    float acc = 0.f;
    #pragma unroll 8
    for (int j = 0; j < 64; j++)
        acc += W[(h * 64 + j) * 1024 + m] * Wi[d * 64 + j];
    out[(size_t)m * 1024 + hd] = acc;
}

// ---------------------------------------------------------------------------
// Stage A: cur[l][n][s][d] = x[b*S+s,:] @ Wc_l   (fp32 tiled GEMM, 64x64x16)
// ---------------------------------------------------------------------------
__global__ __launch_bounds__(256) void k_proj_gemm(
    const float* __restrict__ x, const float* __restrict__ WcAll, float* __restrict__ curAll)
{
    int zi = blockIdx.z;
    const float* Bm = WcAll + (size_t)zi * 1024 * 1024;
    float* out = curAll + (size_t)zi * 64 * 1024 * 64;

    __shared__ float As[16][68];
    __shared__ float Bs[16][68];

    int tid = threadIdx.x;
    int tx = tid & 15, ty = tid >> 4;
    int mt = blockIdx.x;       // 0..63  (rows of x)
    int nt = blockIdx.y;       // 0..15  (64-col block == head nt)
    int rb = mt * 64, cb = nt * 64;

    float c[4][4] = {};
    for (int kb = 0; kb < 1024; kb += 16) {
        #pragma unroll
        for (int i = 0; i < 4; i++) {
            int lin = tid + 256 * i;
            int k = lin & 15, m = lin >> 4;
            As[k][m] = x[(size_t)(rb + m) * 1024 + kb + k];
        }
        #pragma unroll
        for (int i = 0; i < 4; i++) {
            int lin = tid + 256 * i;
            int col = lin & 63, k = lin >> 6;
            Bs[k][col] = Bm[(size_t)(kb + k) * 1024 + cb + col];
        }
        __syncthreads();
        #pragma unroll
        for (int kk = 0; kk < 16; kk++) {
            float a[4], bv[4];
            #pragma unroll
            for (int i = 0; i < 4; i++) a[i] = As[kk][ty * 4 + i];
            #pragma unroll
            for (int j = 0; j < 4; j++) bv[j] = Bs[kk][tx * 4 + j];
            #pragma unroll
            for (int i = 0; i < 4; i++)
                #pragma unroll
                for (int j = 0; j < 4; j++)
                    c[i][j] += a[i] * bv[j];
        }
        __syncthreads();
    }
    // write to cur[n][s][d], n = b*16 + h (h == nt), d = tx*4+j
    #pragma unroll
    for (int i = 0; i < 4; i++) {
        int row = rb + ty * 4 + i;          // b*1024 + s
        int b = row >> 10, s = row & 1023;
        int n = b * 16 + nt;
        float4 v4 = make_float4(c[i][0], c[i][1], c[i][2], c[i][3]);
        *reinterpret_cast<float4*>(&out[((size_t)n * 1024 + s) * 64 + tx * 4]) = v4;
    }
}

// ---------------------------------------------------------------------------
// Stage B: LIF scan. One wave per (l, n). Emits spike bitmask per step.
// total[d] = cur + sum_{j set in mask} W_rec[d][j]  via nibble LUTs in LDS.
// ---------------------------------------------------------------------------
__global__ __launch_bounds__(64) void k_lif(
    const float* __restrict__ curAll,
    const float* __restrict__ Wrq, const float* __restrict__ Wrk, const float* __restrict__ Wrv,
    const float* __restrict__ thq, const float* __restrict__ thk, const float* __restrict__ thv,
    unsigned long long* __restrict__ masks)
{
    __shared__ float T[15 * 16 * 64];   // nibble tables for bits 0..59
    __shared__ float W4[4 * 64];        // direct columns for bits 60..63

    int bid = blockIdx.x;               // 0..191
    int l = bid >> 6, n = bid & 63;
    const float* W  = (l == 0) ? Wrq : (l == 1) ? Wrk : Wrv;
    const float* th = (l == 0) ? thq : (l == 1) ? thk : thv;
    const float* cbase = curAll + (((size_t)l * 64 + n) * 1024) * 64;
    unsigned long long* mout = masks + ((size_t)l * 64 + n) * 1024;
    int d = threadIdx.x;

    for (int g = 0; g < 15; g++) {
        float w0 = W[d * 64 + 4 * g + 0];
        float w1 = W[d * 64 + 4 * g + 1];
        float w2 = W[d * 64 + 4 * g + 2];
        float w3 = W[d * 64 + 4 * g + 3];
        #pragma unroll
        for (int c = 0; c < 16; c++) {
            float t = 0.f;
            if (c & 1) t += w0;
            if (c & 2) t += w1;
            if (c & 4) t += w2;
            if (c & 8) t += w3;
            T[(g * 16 + c) * 64 + d] = t;
        }
    }
    #pragma unroll
    for (int b = 0; b < 4; b++) W4[b * 64 + d] = W[d * 64 + 60 + b];
    __syncthreads();

    float v = 0.f, refrac = 0.f, athr = 1.0f;
    float theta = th[d];
    unsigned long long mask = 0ull;
    float c0 = cbase[0 * 64 + d];
    float c1 = cbase[1 * 64 + d];

    for (int s = 0; s < 1024; s++) {
        float curv = c0;
        c0 = c1;
        c1 = (s + 2 < 1024) ? cbase[(size_t)(s + 2) * 64 + d] : 0.f;

        unsigned mlo = (unsigned)mask;
        unsigned mhi = (unsigned)(mask >> 32);
        float total = curv;
        #pragma unroll
        for (int g = 0; g < 8; g++)
            total += T[(g * 16 + ((mlo >> (4 * g)) & 15)) * 64 + d];
        #pragma unroll
        for (int g = 0; g < 7; g++)
            total += T[((g + 8) * 16 + ((mhi >> (4 * g)) & 15)) * 64 + d];
        unsigned hb = mhi >> 28;
        total += (hb & 1u) ? W4[0 * 64 + d] : 0.f;
        total += (hb & 2u) ? W4[1 * 64 + d] : 0.f;
        total += (hb & 4u) ? W4[2 * 64 + d] : 0.f;
        total += (hb & 8u) ? W4[3 * 64 + d] : 0.f;

        v = 0.9f * v + total;
        v = (refrac <= 0.f) ? v : 0.f;
        bool sp = (v >= athr);
        mask = __ballot(sp);
        float sm = sp ? 1.f : 0.f;
        v = sp ? 0.f : v;
        refrac = fmaxf(refrac - 1.f, sm * 2.f);
        athr = 0.95f * athr + sm * theta;
        if (d == 0) mout[s] = mask;
    }
}

// ---------------------------------------------------------------------------
// Stage C: attention on spike bitmasks. score = popcount(qm & km)/8.
// One thread per q-row; two passes (max, then exp-LUT weighted accumulate).
// ---------------------------------------------------------------------------
__global__ __launch_bounds__(256) void k_attn(
    const unsigned long long* __restrict__ masks, float* __restrict__ ctx)
{
    __shared__ unsigned long long km[1024];
    __shared__ unsigned long long vmv[1024];
    __shared__ float lut[65];

    const unsigned long long* qm_all = masks;
    const unsigned long long* km_all = masks + (size_t)64 * 1024;
    const unsigned long long* vm_all = masks + (size_t)2 * 64 * 1024;

    int blk = blockIdx.x;        // n*4 + chunk
    int n = blk >> 2, chunk = blk & 3;
    int tid = threadIdx.x;

    for (int i = tid; i < 1024; i += 256) {
        km[i]  = km_all[(size_t)n * 1024 + i];
        vmv[i] = vm_all[(size_t)n * 1024 + i];
    }
    if (tid < 65) lut[tid] = expf(-0.125f * (float)tid);
    __syncthreads();

    int r = chunk * 256 + tid;
    unsigned long long qm = qm_all[(size_t)n * 1024 + r];

    int mx = 0;
    for (int s = 0; s < 1024; s++) {
        int cnt = __popcll(qm & km[s]);
        mx = max(mx, cnt);
    }

    float acc[64];
    #pragma unroll
    for (int d2 = 0; d2 < 64; d2++) acc[d2] = 0.f;
    float sum = 0.f;

    for (int s = 0; s < 1024; s++) {
        int cnt = __popcll(qm & km[s]);
        float p = lut[mx - cnt];
        sum += p;
        unsigned long long vm = vmv[s];
        unsigned vlo = __builtin_amdgcn_readfirstlane((unsigned)vm);
        unsigned vhi = __builtin_amdgcn_readfirstlane((unsigned)(vm >> 32));
        #pragma unroll
        for (int d2 = 0; d2 < 32; d2++)
            acc[d2] += (vlo & (1u << d2)) ? p : 0.f;
        #pragma unroll
        for (int d2 = 0; d2 < 32; d2++)
            acc[32 + d2] += (vhi & (1u << d2)) ? p : 0.f;
    }

    float inv = 1.f / sum;
    int b = n >> 4, h = n & 15;
    float* out = ctx + ((size_t)(b * 1024 + r)) * 1024 + h * 64;
    #pragma unroll
    for (int d2 = 0; d2 < 16; d2++) {
        float4 v4 = make_float4(acc[4 * d2 + 0] * inv, acc[4 * d2 + 1] * inv,
                                acc[4 * d2 + 2] * inv, acc[4 * d2 + 3] * inv);
        *reinterpret_cast<float4*>(&out[4 * d2]) = v4;
    }
}

// ---------------------------------------------------------------------------
// Stage D: out = ctx @ Wo.T + bo   (fp32 tiled GEMM, B accessed N-major)
// ---------------------------------------------------------------------------
__global__ __launch_bounds__(256) void k_out_gemm(
    const float* __restrict__ A, const float* __restrict__ Wo,
    const float* __restrict__ bo, float* __restrict__ out)
{
    __shared__ float As[16][68];
    __shared__ float Bs[16][68];

    int tid = threadIdx.x;
    int tx = tid & 15, ty = tid >> 4;
    int mt = blockIdx.x, nt = blockIdx.y;
    int rb = mt * 64, cb = nt * 64;

    float c[4][4] = {};
    for (int kb = 0; kb < 1024; kb += 16) {
        #pragma unroll
        for (int i = 0; i < 4; i++) {
            int lin = tid + 256 * i;
            int k = lin & 15, m = lin >> 4;
            As[k][m] = A[(size_t)(rb + m) * 1024 + kb + k];
        }
        #pragma unroll
        for (int i = 0; i < 4; i++) {
            int lin = tid + 256 * i;
            int k = lin & 15, col = lin >> 4;
            Bs[k][col] = Wo[(size_t)(cb + col) * 1024 + kb + k];
        }
        __syncthreads();
        #pragma unroll
        for (int kk = 0; kk < 16; kk++) {
            float a[4], bv[4];
            #pragma unroll
            for (int i = 0; i < 4; i++) a[i] = As[kk][ty * 4 + i];
            #pragma unroll
            for (int j = 0; j < 4; j++) bv[j] = Bs[kk][tx * 4 + j];
            #pragma unroll
            for (int i = 0; i < 4; i++)
                #pragma unroll
                for (int j = 0; j < 4; j++)
                    c[i][j] += a[i] * bv[j];
        }
        __syncthreads();
    }
    int col = cb + tx * 4;
    float4 bias = *reinterpret_cast<const float4*>(&bo[col]);
    #pragma unroll
    for (int i = 0; i < 4; i++) {
        int row = rb + ty * 4 + i;
        float4 v4 = make_float4(c[i][0] + bias.x, c[i][1] + bias.y,
                                c[i][2] + bias.z, c[i][3] + bias.w);
        *reinterpret_cast<float4*>(&out[(size_t)row * 1024 + col]) = v4;
    }
}

// ---------------------------------------------------------------------------
extern "C" void kernel_launch(void* const* d_in, const int* in_sizes, int n_in,
                              void* d_out, int out_size, void* d_ws, size_t ws_size,
                              hipStream_t stream) {
    const float* x    = (const float*)d_in[0];
    const float* Wq   = (const float*)d_in[1];
    const float* Wk   = (const float*)d_in[2];
    const float* Wv   = (const float*)d_in[3];
    const float* Wo   = (const float*)d_in[4];
    const float* bo   = (const float*)d_in[5];
    const float* Wqi  = (const float*)d_in[6];
    const float* Wqr  = (const float*)d_in[7];
    const float* Wki  = (const float*)d_in[8];
    const float* Wkr  = (const float*)d_in[9];
    const float* Wvi  = (const float*)d_in[10];
    const float* Wvr  = (const float*)d_in[11];
    const float* thq  = (const float*)d_in[12];
    const float* thk  = (const float*)d_in[13];
    const float* thv  = (const float*)d_in[14];

    char* ws = (char*)d_ws;
    float* Wc  = (float*)(ws + WC_OFF);
    float* cur = (float*)(ws + CUR_OFF);
    unsigned long long* masks = (unsigned long long*)(ws + MSK_OFF);
    float* ctx = (float*)(ws + CTX_OFF);
    float* out = (float*)d_out;

    k_wc<<<dim3(4096, 3, 1), 256, 0, stream>>>(Wq, Wk, Wv, Wqi, Wki, Wvi, Wc);
    k_proj_gemm<<<dim3(64, 16, 3), 256, 0, stream>>>(x, Wc, cur);
    k_lif<<<dim3(192, 1, 1), 64, 0, stream>>>(cur, Wqr, Wkr, Wvr, thq, thk, thv, masks);
    k_attn<<<dim3(256, 1, 1), 256, 0, stream>>>(masks, ctx);
    k_out_gemm<<<dim3(64, 16, 1), 256, 0, stream>>>(ctx, Wo, bo, out);
}

// Round 2
// 977.562 us; speedup vs baseline: 1.5207x; 1.5207x over previous
//
#include <hip/hip_runtime.h>
#include <hip/hip_bf16.h>

// Problem constants
#define B_  4
#define S_  1024
#define D_  1024
#define H_  16
#define DH_ 64
#define N_  64          // B*H
#define BS_ 4096        // B*S

// Workspace layout (bytes)
#define WC_OFF   0ull                                // 3 x 1M floats = 12 MB
#define CUR_OFF  (WC_OFF + 3ull*1024*1024*4)         // 3 x [64][1024][64] f32 = 48 MB
#define MSK_OFF  (CUR_OFF + 3ull*64*1024*64*4)       // 3 x [64][1024] u64 = 1.5 MB
#define CTX_OFF  (MSK_OFF + 3ull*64*1024*8)          // [4096][1024] f32 = 16 MB

typedef __attribute__((ext_vector_type(8))) short short8v;
typedef __attribute__((ext_vector_type(4))) float f32x4;

// ---------------------------------------------------------------------------
// Stage 0: combined projection weights Wc[m][h*64+d] = sum_j W[h*64+j][m] * Win[d][j]
// ---------------------------------------------------------------------------
__global__ __launch_bounds__(256) void k_wc(
    const float* __restrict__ Wq, const float* __restrict__ Wk, const float* __restrict__ Wv,
    const float* __restrict__ Wqi, const float* __restrict__ Wki, const float* __restrict__ Wvi,
    float* __restrict__ Wc)
{
    int z = blockIdx.y;
    const float* W  = (z == 0) ? Wq  : (z == 1) ? Wk  : Wv;
    const float* Wi = (z == 0) ? Wqi : (z == 1) ? Wki : Wvi;
    float* out = Wc + (size_t)z * 1024 * 1024;
    int o  = blockIdx.x * 256 + threadIdx.x;   // 0..1M-1
    int m  = o >> 10;
    int hd = o & 1023;
    int h  = hd >> 6, d = hd & 63;
    float acc = 0.f;
    #pragma unroll 8
    for (int j = 0; j < 64; j++)
        acc += W[(h * 64 + j) * 1024 + m] * Wi[d * 64 + j];
    out[(size_t)m * 1024 + hd] = acc;
}

// ---------------------------------------------------------------------------
// Stage A: cur[l][n][s][d] = x[b*S+s,:] @ Wc_l   (fp32 tiled GEMM, 64x64x16)
// ---------------------------------------------------------------------------
__global__ __launch_bounds__(256) void k_proj_gemm(
    const float* __restrict__ x, const float* __restrict__ WcAll, float* __restrict__ curAll)
{
    int zi = blockIdx.z;
    const float* Bm = WcAll + (size_t)zi * 1024 * 1024;
    float* out = curAll + (size_t)zi * 64 * 1024 * 64;

    __shared__ float As[16][68];
    __shared__ float Bs[16][68];

    int tid = threadIdx.x;
    int tx = tid & 15, ty = tid >> 4;
    int mt = blockIdx.x;       // 0..63  (rows of x)
    int nt = blockIdx.y;       // 0..15  (64-col block == head nt)
    int rb = mt * 64, cb = nt * 64;

    float c[4][4] = {};
    for (int kb = 0; kb < 1024; kb += 16) {
        #pragma unroll
        for (int i = 0; i < 4; i++) {
            int lin = tid + 256 * i;
            int k = lin & 15, m = lin >> 4;
            As[k][m] = x[(size_t)(rb + m) * 1024 + kb + k];
        }
        #pragma unroll
        for (int i = 0; i < 4; i++) {
            int lin = tid + 256 * i;
            int col = lin & 63, k = lin >> 6;
            Bs[k][col] = Bm[(size_t)(kb + k) * 1024 + cb + col];
        }
        __syncthreads();
        #pragma unroll
        for (int kk = 0; kk < 16; kk++) {
            float a[4], bv[4];
            #pragma unroll
            for (int i = 0; i < 4; i++) a[i] = As[kk][ty * 4 + i];
            #pragma unroll
            for (int j = 0; j < 4; j++) bv[j] = Bs[kk][tx * 4 + j];
            #pragma unroll
            for (int i = 0; i < 4; i++)
                #pragma unroll
                for (int j = 0; j < 4; j++)
                    c[i][j] += a[i] * bv[j];
        }
        __syncthreads();
    }
    #pragma unroll
    for (int i = 0; i < 4; i++) {
        int row = rb + ty * 4 + i;          // b*1024 + s
        int b = row >> 10, s = row & 1023;
        int n = b * 16 + nt;
        float4 v4 = make_float4(c[i][0], c[i][1], c[i][2], c[i][3]);
        *reinterpret_cast<float4*>(&out[((size_t)n * 1024 + s) * 64 + tx * 4]) = v4;
    }
}

// ---------------------------------------------------------------------------
// Stage B: LIF scan. One wave per (l, n). Emits spike bitmask per step.
// ---------------------------------------------------------------------------
__global__ __launch_bounds__(64) void k_lif(
    const float* __restrict__ curAll,
    const float* __restrict__ Wrq, const float* __restrict__ Wrk, const float* __restrict__ Wrv,
    const float* __restrict__ thq, const float* __restrict__ thk, const float* __restrict__ thv,
    unsigned long long* __restrict__ masks)
{
    __shared__ float T[15 * 16 * 64];   // nibble tables for bits 0..59
    __shared__ float W4[4 * 64];        // direct columns for bits 60..63

    int bid = blockIdx.x;               // 0..191
    int l = bid >> 6, n = bid & 63;
    const float* W  = (l == 0) ? Wrq : (l == 1) ? Wrk : Wrv;
    const float* th = (l == 0) ? thq : (l == 1) ? thk : thv;
    const float* cbase = curAll + (((size_t)l * 64 + n) * 1024) * 64;
    unsigned long long* mout = masks + ((size_t)l * 64 + n) * 1024;
    int d = threadIdx.x;

    for (int g = 0; g < 15; g++) {
        float w0 = W[d * 64 + 4 * g + 0];
        float w1 = W[d * 64 + 4 * g + 1];
        float w2 = W[d * 64 + 4 * g + 2];
        float w3 = W[d * 64 + 4 * g + 3];
        #pragma unroll
        for (int c = 0; c < 16; c++) {
            float t = 0.f;
            if (c & 1) t += w0;
            if (c & 2) t += w1;
            if (c & 4) t += w2;
            if (c & 8) t += w3;
            T[(g * 16 + c) * 64 + d] = t;
        }
    }
    #pragma unroll
    for (int b = 0; b < 4; b++) W4[b * 64 + d] = W[d * 64 + 60 + b];
    __syncthreads();

    float v = 0.f, refrac = 0.f, athr = 1.0f;
    float theta = th[d];
    unsigned long long mask = 0ull;
    float c0 = cbase[0 * 64 + d];
    float c1 = cbase[1 * 64 + d];

    for (int s = 0; s < 1024; s++) {
        float curv = c0;
        c0 = c1;
        c1 = (s + 2 < 1024) ? cbase[(size_t)(s + 2) * 64 + d] : 0.f;

        unsigned mlo = (unsigned)mask;
        unsigned mhi = (unsigned)(mask >> 32);
        float total = curv;
        #pragma unroll
        for (int g = 0; g < 8; g++)
            total += T[(g * 16 + ((mlo >> (4 * g)) & 15)) * 64 + d];
        #pragma unroll
        for (int g = 0; g < 7; g++)
            total += T[((g + 8) * 16 + ((mhi >> (4 * g)) & 15)) * 64 + d];
        unsigned hb = mhi >> 28;
        total += (hb & 1u) ? W4[0 * 64 + d] : 0.f;
        total += (hb & 2u) ? W4[1 * 64 + d] : 0.f;
        total += (hb & 4u) ? W4[2 * 64 + d] : 0.f;
        total += (hb & 8u) ? W4[3 * 64 + d] : 0.f;

        v = 0.9f * v + total;
        v = (refrac <= 0.f) ? v : 0.f;
        bool sp = (v >= athr);
        mask = __ballot(sp);
        float sm = sp ? 1.f : 0.f;
        v = sp ? 0.f : v;
        refrac = fmaxf(refrac - 1.f, sm * 2.f);
        athr = 0.95f * athr + sm * theta;
        if (d == 0) mout[s] = mask;
    }
}

// ---------------------------------------------------------------------------
// Stage C: MFMA attention on spike bitmasks.
// Per block: one head, 64 q rows (4 waves x 16). Loop over 8 k-tiles of 128.
// S^T = mfma(K_tile, Q) so C-frag col = q. p = exp2(cnt*c1 - c2) (no row max
// needed: score <= 8). PV: ctx^T = mfma(V^T, P^T); P^T B-frags built from the
// S^T C-frags via 8 shfl + 4 selects per 32-k chunk (pure permutation).
// K_lds [128][64+8], Vt [64][128+8] padded: even 8-lane/16B-window bank spread.
// ---------------------------------------------------------------------------
#define ATT_C1 0.180336879f    // 0.125 * log2(e)
#define ATT_C2 11.541560327f   // 8 * log2(e)

__device__ inline short8v expand8(unsigned byte) {
    short8v r;
    #pragma unroll
    for (int e = 0; e < 8; e++)
        r[e] = (short)(((byte >> e) & 1u) ? 0x3F80 : 0);
    return r;
}

__device__ inline unsigned bfpk(float x, float y) {
    unsigned ux = __float_as_uint(x);
    unsigned uy = __float_as_uint(y);
    unsigned rx = (ux + 0x7FFFu + ((ux >> 16) & 1u)) >> 16;
    unsigned ry = (uy + 0x7FFFu + ((uy >> 16) & 1u)) >> 16;
    return rx | (ry << 16);
}

__global__ __launch_bounds__(256) void k_attn_mfma(
    const unsigned long long* __restrict__ masks, float* __restrict__ ctx)
{
    __shared__ __align__(16) unsigned short Klds[128][72];   // bf16 bits, +8 pad
    __shared__ __align__(16) unsigned short Vt[64][136];     // V^T, +8 pad
    __shared__ unsigned long long vmbuf[2][128];

    const unsigned long long* qm_all = masks;
    const unsigned long long* km_all = masks + (size_t)64 * 1024;
    const unsigned long long* vm_all = masks + (size_t)2 * 64 * 1024;

    int n  = blockIdx.y;       // head (b*16+h)
    int qc = blockIdx.x;       // q chunk of 64 rows
    int tid = threadIdx.x;
    int wv = tid >> 6;
    int lane = tid & 63;
    int r15 = lane & 15, g = lane >> 4;

    const unsigned long long* km = km_all + (size_t)n * 1024;
    const unsigned long long* vm = vm_all + (size_t)n * 1024;

    // Q fragments: built from bits of this wave's q-row masks (kept in regs)
    unsigned long long qmask = qm_all[(size_t)n * 1024 + qc * 64 + wv * 16 + r15];
    short8v Qf[2];
    #pragma unroll
    for (int ch = 0; ch < 2; ch++)
        Qf[ch] = expand8((unsigned)(qmask >> ((ch * 4 + g) * 8)) & 0xFFu);

    f32x4 cx[4];
    #pragma unroll
    for (int mt = 0; mt < 4; mt++) cx[mt] = (f32x4){0.f, 0.f, 0.f, 0.f};
    float den = 0.f;

    // prologue: stage vm tile 0
    if (tid < 128) vmbuf[0][tid] = vm[tid];
    __syncthreads();

    for (int kt = 0; kt < 8; kt++) {
        // ---- Phase A: expand K tile and V^T tile into LDS ----
        {
            int s = tid >> 1, half = tid & 1;
            unsigned long long m = km[kt * 128 + s];
            #pragma unroll
            for (int j = 0; j < 4; j++) {
                unsigned byte = (unsigned)(m >> (half * 32 + j * 8)) & 0xFFu;
                *reinterpret_cast<short8v*>(&Klds[s][(half * 4 + j) * 8]) = expand8(byte);
            }
        }
        {
            int dh = tid & 63;
            int sc4 = tid >> 6;          // wave id == s-chunk of 32
            #pragma unroll
            for (int j = 0; j < 4; j++) {
                short8v v;
                #pragma unroll
                for (int e = 0; e < 8; e++) {
                    unsigned long long mv = vmbuf[kt & 1][sc4 * 32 + j * 8 + e];
                    v[e] = (short)(((mv >> dh) & 1ull) ? 0x3F80 : 0);
                }
                *reinterpret_cast<short8v*>(&Vt[dh][(sc4 * 4 + j) * 8]) = v;
            }
        }
        __syncthreads();

        // stage next tile's vm during compute
        if (tid < 128 && kt + 1 < 8) vmbuf[(kt + 1) & 1][tid] = vm[(kt + 1) * 128 + tid];

        // ---- Phase B: compute ----
        // QK^T (S^T orientation): 8 M-tiles of 16 s-rows
        f32x4 pf[8];
        #pragma unroll
        for (int mt = 0; mt < 8; mt++) {
            f32x4 c = (f32x4){0.f, 0.f, 0.f, 0.f};
            #pragma unroll
            for (int ch = 0; ch < 2; ch++) {
                short8v a = *reinterpret_cast<const short8v*>(&Klds[mt * 16 + r15][(ch * 4 + g) * 8]);
                c = __builtin_amdgcn_mfma_f32_16x16x32_bf16(a, Qf[ch], c, 0, 0, 0);
            }
            f32x4 p;
            #pragma unroll
            for (int i = 0; i < 4; i++) {
                p[i] = exp2f(c[i] * ATT_C1 - ATT_C2);
                den += p[i];
            }
            pf[mt] = p;
        }

        // PV: ctx^T += V^T @ P^T, 4 k-chunks of 32
        int src0 = ((g & 1) << 1) * 16 + r15;
        int src1 = src0 + 16;
        bool hi = (g >= 2);
        #pragma unroll
        for (int c4 = 0; c4 < 4; c4++) {
            unsigned d0 = bfpk(pf[2 * c4][0], pf[2 * c4][1]);
            unsigned d1 = bfpk(pf[2 * c4][2], pf[2 * c4][3]);
            unsigned d2 = bfpk(pf[2 * c4 + 1][0], pf[2 * c4 + 1][1]);
            unsigned d3 = bfpk(pf[2 * c4 + 1][2], pf[2 * c4 + 1][3]);
            unsigned a0 = __shfl((int)d0, src0), b0 = __shfl((int)d2, src0);
            unsigned a1 = __shfl((int)d1, src0), b1 = __shfl((int)d3, src0);
            unsigned a2 = __shfl((int)d0, src1), b2 = __shfl((int)d2, src1);
            unsigned a3 = __shfl((int)d1, src1), b3 = __shfl((int)d3, src1);
            union { unsigned u[4]; short8v s; } bw;
            bw.u[0] = hi ? b0 : a0;
            bw.u[1] = hi ? b1 : a1;
            bw.u[2] = hi ? b2 : a2;
            bw.u[3] = hi ? b3 : a3;
            #pragma unroll
            for (int mt = 0; mt < 4; mt++) {
                short8v a = *reinterpret_cast<const short8v*>(&Vt[mt * 16 + r15][(c4 * 4 + g) * 8]);
                cx[mt] = __builtin_amdgcn_mfma_f32_16x16x32_bf16(a, bw.s, cx[mt], 0, 0, 0);
            }
        }
        __syncthreads();
    }

    // reduce den across the 4 lane-groups (per q column)
    den += __shfl_xor(den, 16);
    den += __shfl_xor(den, 32);
    float inv = 1.f / den;

    int b = n >> 4, h = n & 15;
    int row = b * 1024 + qc * 64 + wv * 16 + r15;
    float* op = ctx + (size_t)row * 1024 + h * 64;
    #pragma unroll
    for (int mt = 0; mt < 4; mt++)
        #pragma unroll
        for (int i = 0; i < 4; i++)
            op[mt * 16 + g * 4 + i] = cx[mt][i] * inv;
}

// ---------------------------------------------------------------------------
// Stage D: out = ctx @ Wo.T + bo   (fp32 tiled GEMM)
// ---------------------------------------------------------------------------
__global__ __launch_bounds__(256) void k_out_gemm(
    const float* __restrict__ A, const float* __restrict__ Wo,
    const float* __restrict__ bo, float* __restrict__ out)
{
    __shared__ float As[16][68];
    __shared__ float Bs[16][68];

    int tid = threadIdx.x;
    int tx = tid & 15, ty = tid >> 4;
    int mt = blockIdx.x, nt = blockIdx.y;
    int rb = mt * 64, cb = nt * 64;

    float c[4][4] = {};
    for (int kb = 0; kb < 1024; kb += 16) {
        #pragma unroll
        for (int i = 0; i < 4; i++) {
            int lin = tid + 256 * i;
            int k = lin & 15, m = lin >> 4;
            As[k][m] = A[(size_t)(rb + m) * 1024 + kb + k];
        }
        #pragma unroll
        for (int i = 0; i < 4; i++) {
            int lin = tid + 256 * i;
            int k = lin & 15, col = lin >> 4;
            Bs[k][col] = Wo[(size_t)(cb + col) * 1024 + kb + k];
        }
        __syncthreads();
        #pragma unroll
        for (int kk = 0; kk < 16; kk++) {
            float a[4], bv[4];
            #pragma unroll
            for (int i = 0; i < 4; i++) a[i] = As[kk][ty * 4 + i];
            #pragma unroll
            for (int j = 0; j < 4; j++) bv[j] = Bs[kk][tx * 4 + j];
            #pragma unroll
            for (int i = 0; i < 4; i++)
                #pragma unroll
                for (int j = 0; j < 4; j++)
                    c[i][j] += a[i] * bv[j];
        }
        __syncthreads();
    }
    int col = cb + tx * 4;
    float4 bias = *reinterpret_cast<const float4*>(&bo[col]);
    #pragma unroll
    for (int i = 0; i < 4; i++) {
        int row = rb + ty * 4 + i;
        float4 v4 = make_float4(c[i][0] + bias.x, c[i][1] + bias.y,
                                c[i][2] + bias.z, c[i][3] + bias.w);
        *reinterpret_cast<float4*>(&out[(size_t)row * 1024 + col]) = v4;
    }
}

// ---------------------------------------------------------------------------
extern "C" void kernel_launch(void* const* d_in, const int* in_sizes, int n_in,
                              void* d_out, int out_size, void* d_ws, size_t ws_size,
                              hipStream_t stream) {
    const float* x    = (const float*)d_in[0];
    const float* Wq   = (const float*)d_in[1];
    const float* Wk   = (const float*)d_in[2];
    const float* Wv   = (const float*)d_in[3];
    const float* Wo   = (const float*)d_in[4];
    const float* bo   = (const float*)d_in[5];
    const float* Wqi  = (const float*)d_in[6];
    const float* Wqr  = (const float*)d_in[7];
    const float* Wki  = (const float*)d_in[8];
    const float* Wkr  = (const float*)d_in[9];
    const float* Wvi  = (const float*)d_in[10];
    const float* Wvr  = (const float*)d_in[11];
    const float* thq  = (const float*)d_in[12];
    const float* thk  = (const float*)d_in[13];
    const float* thv  = (const float*)d_in[14];

    char* ws = (char*)d_ws;
    float* Wc  = (float*)(ws + WC_OFF);
    float* cur = (float*)(ws + CUR_OFF);
    unsigned long long* masks = (unsigned long long*)(ws + MSK_OFF);
    float* ctx = (float*)(ws + CTX_OFF);
    float* out = (float*)d_out;

    k_wc<<<dim3(4096, 3, 1), 256, 0, stream>>>(Wq, Wk, Wv, Wqi, Wki, Wvi, Wc);
    k_proj_gemm<<<dim3(64, 16, 3), 256, 0, stream>>>(x, Wc, cur);
    k_lif<<<dim3(192, 1, 1), 64, 0, stream>>>(cur, Wqr, Wkr, Wvr, thq, thk, thv, masks);
    k_attn_mfma<<<dim3(16, 64, 1), 256, 0, stream>>>(masks, ctx);
    k_out_gemm<<<dim3(64, 16, 1), 256, 0, stream>>>(ctx, Wo, bo, out);
}